// Round 8
// baseline (302.437 us; speedup 1.0000x reference)
//
#include <hip/hip_runtime.h>
#include <hip/hip_bf16.h>
#include <hip/hip_fp16.h>
#include <math.h>

#define NN 50000
#define EE 1600000
#define GG 512
#define INDIM 128
#define HEADS 3
#define CC 32
#define DD 96            // HEADS*CC
#define HID 512
#define NEG 0.2f
#define EPS_DEN 1e-16f
#define CAP 128          // fixed CSR row capacity (mean degree 32, sigma 5.7 -> 17 sigma headroom)
#define MNEG -1e30f      // empty-partial sentinel (finite: avoids -inf-(-inf)=NaN in merges)

// packed fp32 param block offsets (in floats)
#define OFF_WL1   0
#define OFF_BL1   12288
#define OFF_WR1   12384
#define OFF_BR1   24672
#define OFF_ATT1  24768
#define OFF_BIAS1 24864
#define OFF_WL2   24960
#define OFF_BL2   34176
#define OFF_WR2   34272
#define OFF_BR2   43488
#define OFF_ATT2  43584
#define OFF_BIAS2 43680
#define OFF_WFC1  43776
#define OFF_BFC1  142080
#define OFF_WFC2  142592
#define OFF_BFC2  143616
#define P_TOTAL   143744

typedef _Float16 h8 __attribute__((ext_vector_type(8)));
typedef float f4 __attribute__((ext_vector_type(4)));

static __device__ __forceinline__ float bf2f(__hip_bfloat16 v) { return __bfloat162float(v); }

// index fetch tolerant of int64-vs-int32 storage (little-endian, values < 2^31)
static __device__ __forceinline__ int getI(const void* p, long long i, bool w64) {
    return w64 ? ((const int*)p)[2 * i] : ((const int*)p)[i];
}

// load 4 consecutive edge indices starting at element (base+e0); e0 multiple of 4, base even
static __device__ __forceinline__ void load4(const void* p, int base, int e0, bool w64, int* v) {
    const int4* q = (const int4*)p;
    if (w64) {
        int4 a = q[(base + e0) >> 1];
        int4 b = q[((base + e0) >> 1) + 1];
        v[0] = a.x; v[1] = a.z; v[2] = b.x; v[3] = b.z;
    } else {
        int4 a = q[(base + e0) >> 2];
        v[0] = a.x; v[1] = a.y; v[2] = a.z; v[3] = a.w;
    }
}

// ---------------- dtype detection ----------------
__global__ void detect_kernel(const void* __restrict__ x, const void* __restrict__ ei,
                              int* __restrict__ flags)
{
    __shared__ int wild, zcnt;
    if (threadIdx.x == 0) { wild = 0; zcnt = 0; }
    __syncthreads();
    int w = 0, z = 0;
    const __hip_bfloat16* xb = (const __hip_bfloat16*)x;
    for (int i = threadIdx.x; i < 4096; i += 256) {
        float v = bf2f(xb[i]);
        if (!(fabsf(v) <= 1e6f)) w++;
    }
    const int* e32 = (const int*)ei;
    for (int i = threadIdx.x; i < 4096; i += 256) {
        if (e32[2 * i + 1] == 0) z++;
    }
    atomicAdd(&wild, w);
    atomicAdd(&zcnt, z);
    __syncthreads();
    if (threadIdx.x == 0) {
        flags[0] = (wild < 64) ? 1 : 0;   // 1 => floats are bf16
        flags[1] = (zcnt > 4000) ? 1 : 0; // 1 => ints are int64
    }
}

// ---------------- convert all weight tensors to packed fp32 ----------------
struct ParamTab { const void* p[16]; int sz[16]; int off[16]; };

__global__ void convert_params_kernel(ParamTab t, const int* __restrict__ flags,
                                      float* __restrict__ P)
{
    const int which = blockIdx.y;
    const int n = t.sz[which];
    const void* src = t.p[which];
    float* dst = P + t.off[which];
    const bool isbf = flags[0] != 0;
    for (int i = blockIdx.x * 256 + threadIdx.x; i < n; i += gridDim.x * 256) {
        dst[i] = isbf ? bf2f(((const __hip_bfloat16*)src)[i]) : ((const float*)src)[i];
    }
}

// ---------------- build MFMA-swizzled fp16 B matrix (Wl | Wr), [ntile][kc][lane][8] ----------------
__global__ void build_bswz_kernel(const float* __restrict__ P, int offWl, int offWr, int KC,
                                  __half* __restrict__ B)
{
    int idx = blockIdx.x * 256 + threadIdx.x;
    int total = 12 * KC * 64;
    if (idx >= total) return;
    int lane = idx & 63;
    int t = idx >> 6;
    int kc = t % KC;
    int ntile = t / KC;
    int n = ntile * 16 + (lane & 15);
    int kbase = kc * 32 + (lane >> 4) * 8;
    const float* Wsrc = (n < 96) ? (P + offWl) : (P + offWr);
    int n2 = (n < 96) ? n : n - 96;
    __half* dst = B + (size_t)idx * 8;
#pragma unroll
    for (int j = 0; j < 8; j++) dst[j] = __float2half(Wsrc[(kbase + j) * 96 + n2]);
}

// ---------------- convert x to fp16 ----------------
__global__ void conv_x_kernel(const void* __restrict__ x, const int* __restrict__ flags,
                              __half* __restrict__ xh)
{
    const bool isbf = flags[0] != 0;
    int i0 = (blockIdx.x * 256 + threadIdx.x) * 4;
    if (i0 >= NN * INDIM) return;
#pragma unroll
    for (int j = 0; j < 4; j++) {
        int i = i0 + j;
        float v = isbf ? bf2f(((const __hip_bfloat16*)x)[i]) : ((const float*)x)[i];
        xh[i] = __float2half(v);
    }
}

// ---------------- pooling set ----------------
__global__ void firstpool_kernel(const void* __restrict__ batch, const int* __restrict__ flags,
                                 int* __restrict__ first, int* __restrict__ pooled,
                                 int* __restrict__ needed)
{
    int i = blockIdx.x * 256 + threadIdx.x;
    if (i >= NN) return;
    const bool w64 = flags[1] != 0;
    int b = getI(batch, i, w64);
    if (i == 0 || getI(batch, i - 1, w64) != b) {
        first[b] = i;
        pooled[i] = 1;
        needed[i] = 1;
    }
}

// needed[src]=1 for every edge landing on a pooled dst (4 edges/thread)
__global__ void mark_needed_kernel(const void* __restrict__ ei, const int* __restrict__ flags,
                                   const int* __restrict__ pooled, int* __restrict__ needed)
{
    int e0 = (blockIdx.x * 256 + threadIdx.x) * 4;
    if (e0 >= EE) return;
    const bool w64 = flags[1] != 0;
    int s4[4], d4[4];
    load4(ei, EE, e0, w64, d4);
    load4(ei, 0, e0, w64, s4);
#pragma unroll
    for (int j = 0; j < 4; j++) if (pooled[d4[j]]) needed[s4[j]] = 1;
}

__global__ void compact_kernel(const int* __restrict__ needed, int* __restrict__ list,
                               int* __restrict__ cnt)
{
    int i = blockIdx.x * 256 + threadIdx.x;
    if (i >= NN) return;
    if (needed[i]) list[atomicAdd(cnt, 1)] = i;
}

// ---------------- filtered fixed-stride CSR scatter (4 edges/thread) ----------------
__global__ void scatter_fixed_kernel(const void* __restrict__ ei, const int* __restrict__ flags,
                                     const int* __restrict__ needed,
                                     int* __restrict__ deg, int* __restrict__ csr)
{
    int e0 = (blockIdx.x * 256 + threadIdx.x) * 4;
    if (e0 >= EE) return;
    const bool w64 = flags[1] != 0;
    int s4[4], d4[4];
    load4(ei, EE, e0, w64, d4);
    load4(ei, 0, e0, w64, s4);
#pragma unroll
    for (int j = 0; j < 4; j++) {
        int dst = d4[j];
        if (!needed[dst]) continue;
        int pos = atomicAdd(&deg[dst], 1);
        if (pos < CAP) csr[(size_t)dst * CAP + pos] = s4[j];
    }
}

// ---------------- MFMA projection: rows @ (Wl|Wr)[K,192] + b -> xl (fp16), xr (fp32) ----------------
template <int KDIM, int MODE>
__global__ __launch_bounds__(256) void proj_mfma_kernel(
    const __half* __restrict__ Ain, const __half* __restrict__ Bswz,
    const int* __restrict__ list, const int* __restrict__ cnt,
    const float* __restrict__ P, int offBl, int offBr,
    __half* __restrict__ xl, float* __restrict__ xr)
{
    constexpr int KC = KDIM / 32;
    __shared__ __half Bs[12 * KC * 64 * 8];
    const int tid = threadIdx.x;
    const int limit = MODE ? *cnt : NN;
    const int blockBase = blockIdx.x * 64;
    if (blockBase >= limit) return;

    {
        const int chunks = 12 * KC * 64;
        for (int i = tid; i < chunks; i += 256)
            reinterpret_cast<f4*>(Bs)[i] = reinterpret_cast<const f4*>(Bswz)[i];
    }
    __syncthreads();

    const int wave = tid >> 6;
    const int lane = tid & 63;
    const int base = blockBase + wave * 16;
    if (base >= limit) return;

    const int q = lane >> 4;
    const int mlane = lane & 15;

    int aIdx = base + mlane;
    int aRow;
    if (MODE) aRow = (aIdx < limit) ? list[aIdx] : list[limit - 1];
    else      aRow = (aIdx < limit) ? aIdx : 0;

    h8 a[KC];
    const h8* arow = reinterpret_cast<const h8*>(Ain + (size_t)aRow * KDIM);
#pragma unroll
    for (int kc = 0; kc < KC; kc++) a[kc] = arow[kc * 4 + q];

    int sRow[4];
#pragma unroll
    for (int r = 0; r < 4; r++) {
        int si = base + q * 4 + r;
        sRow[r] = (si < limit) ? (MODE ? list[si] : si) : -1;
    }

    const h8* Bf = reinterpret_cast<const h8*>(Bs);
#pragma unroll
    for (int ntile = 0; ntile < 12; ntile++) {
        int n = ntile * 16 + mlane;
        float bv = (n < 96) ? P[offBl + n] : P[offBr + n - 96];
        f4 acc = {bv, bv, bv, bv};
#pragma unroll
        for (int kc = 0; kc < KC; kc++) {
            h8 b = Bf[(ntile * KC + kc) * 64 + lane];
            acc = __builtin_amdgcn_mfma_f32_16x16x32_f16(a[kc], b, acc, 0, 0, 0);
        }
#pragma unroll
        for (int r = 0; r < 4; r++) {
            if (sRow[r] < 0) continue;
            if (n < 96) xl[(size_t)sRow[r] * DD + n] = __float2half(acc[r]);
            else        xr[(size_t)sRow[r] * DD + (n - 96)] = acc[r];
        }
    }
}

// ---------------- fused edge: quad-per-edge online softmax + aggregate + tanh ----------------
// One wave per (dst, head). Each 4-lane quad owns one edge at a time (lane owns 8 channels);
// 16 independent partials per wave, merged by butterfly at the end.
// OUTMODE 0: dst from list[0..*cnt), output fp16 h1h[node*DD+..]
// OUTMODE 1: dst = first[g], g in [0,GG), output fp32 h2p[g*DD+..]
template <int OUTMODE>
__global__ __launch_bounds__(256) void fused_edge_kernel(
    const int* __restrict__ csr, const int* __restrict__ deg,
    const int* __restrict__ list, const int* __restrict__ cnt,
    const __half* __restrict__ xl, const float* __restrict__ xr,
    const float* __restrict__ P, int offAtt, int offBias,
    void* __restrict__ out)
{
    const int lane = threadIdx.x & 63;
    const int g  = lane >> 2;   // quad id 0..15
    const int ql = lane & 3;    // lane in quad (owns channels ql*8..ql*8+7)
    const int w0 = (blockIdx.x * 256 + threadIdx.x) >> 6;
    const int nw = (gridDim.x * 256) >> 6;
    const int limit = (OUTMODE == 0) ? *cnt : GG;
    const int items = limit * 3;

    for (int item = w0; item < items; item += nw) {
        const int li = item / 3;
        const int h = item - li * 3;
        const int n = list[li];
        const int cb = h * CC + ql * 8;

        float att8[8], xr8[8];
        {
            const f4* ap = reinterpret_cast<const f4*>(P + offAtt + cb);
            *reinterpret_cast<f4*>(&att8[0]) = ap[0];
            *reinterpret_cast<f4*>(&att8[4]) = ap[1];
            const f4* xp = reinterpret_cast<const f4*>(xr + (size_t)n * DD + cb);
            *reinterpret_cast<f4*>(&xr8[0]) = xp[0];
            *reinterpret_cast<f4*>(&xr8[4]) = xp[1];
        }

        float m = MNEG, d = 0.0f, o8[8];
#pragma unroll
        for (int j = 0; j < 8; j++) o8[j] = 0.0f;

        const int* row = csr + (size_t)n * CAP;
        const int end = min(deg[n], CAP);

        // quad 0 handles the self-loop first
        if (g == 0) {
            h8 xh = *reinterpret_cast<const h8*>(xl + (size_t)n * DD + cb);
            float xv8[8];
#pragma unroll
            for (int j = 0; j < 8; j++) xv8[j] = (float)xh[j];
            float p = 0.0f;
#pragma unroll
            for (int j = 0; j < 8; j++) {
                float s = xv8[j] + xr8[j];
                s = s > 0.0f ? s : NEG * s;
                p = fmaf(s, att8[j], p);
            }
            p += __shfl_xor(p, 1);
            p += __shfl_xor(p, 2);
            m = p; d = 1.0f;
#pragma unroll
            for (int j = 0; j < 8; j++) o8[j] = xv8[j];
        }

        for (int k = g; k < end; k += 16) {
            int src = row[k];
            h8 xh = *reinterpret_cast<const h8*>(xl + (size_t)src * DD + cb);
            float xv8[8];
#pragma unroll
            for (int j = 0; j < 8; j++) xv8[j] = (float)xh[j];
            float p = 0.0f;
#pragma unroll
            for (int j = 0; j < 8; j++) {
                float s = xv8[j] + xr8[j];
                s = s > 0.0f ? s : NEG * s;
                p = fmaf(s, att8[j], p);
            }
            p += __shfl_xor(p, 1);
            p += __shfl_xor(p, 2);
            if (p <= m) {
                float e = __expf(p - m);
                d += e;
#pragma unroll
                for (int j = 0; j < 8; j++) o8[j] = fmaf(e, xv8[j], o8[j]);
            } else {
                float r = __expf(m - p);
                d = fmaf(d, r, 1.0f);
#pragma unroll
                for (int j = 0; j < 8; j++) o8[j] = fmaf(o8[j], r, xv8[j]);
                m = p;
            }
        }

        // merge 16 quad partials (butterfly over quads)
#pragma unroll
        for (int off = 4; off <= 32; off <<= 1) {
            float m2 = __shfl_xor(m, off);
            float d2 = __shfl_xor(d, off);
            float o2[8];
#pragma unroll
            for (int j = 0; j < 8; j++) o2[j] = __shfl_xor(o8[j], off);
            float nm = fmaxf(m, m2);
            float e1 = __expf(m - nm), e2 = __expf(m2 - nm);
            d = d * e1 + d2 * e2;
#pragma unroll
            for (int j = 0; j < 8; j++) o8[j] = o8[j] * e1 + o2[j] * e2;
            m = nm;
        }

        if (g == 0) {
            float inv = 1.0f / (d + EPS_DEN);
            float res[8];
#pragma unroll
            for (int j = 0; j < 8; j++) res[j] = tanhf(o8[j] * inv + P[offBias + cb + j]);
            if (OUTMODE == 0) {
                h8 r;
#pragma unroll
                for (int j = 0; j < 8; j++) r[j] = (_Float16)res[j];
                *reinterpret_cast<h8*>((__half*)out + (size_t)n * DD + cb) = r;
            } else {
                float* po = (float*)out + (size_t)li * DD + cb;
                *reinterpret_cast<f4*>(po) = *reinterpret_cast<f4*>(&res[0]);
                *reinterpret_cast<f4*>(po + 4) = *reinterpret_cast<f4*>(&res[4]);
            }
        }
    }
}

// ---------------- per-graph MLP head + log_softmax ----------------
__global__ __launch_bounds__(256) void mlp_kernel(
    const __half* __restrict__ h1h, const float* __restrict__ h2p,
    const float* __restrict__ P, const int* __restrict__ flags,
    const int* __restrict__ first, void* __restrict__ outv)
{
    __shared__ float pooled[2 * DD];
    __shared__ float hidden[HID];
    __shared__ float r0[4], r1[4];
    const int g = blockIdx.x;
    const int t = threadIdx.x;
    const int row = first[g];

    if (t < DD) pooled[t] = __half2float(h1h[(size_t)row * DD + t]);
    else if (t < 2 * DD) pooled[t] = h2p[(size_t)g * DD + (t - DD)];
    __syncthreads();

    for (int col = t; col < HID; col += 256) {
        float acc = P[OFF_BFC1 + col];
        for (int i = 0; i < 2 * DD; i++) acc += pooled[i] * P[OFF_WFC1 + i * HID + col];
        hidden[col] = fmaxf(acc, 0.0f);
    }
    __syncthreads();

    float p0 = 0.0f, p1 = 0.0f;
    for (int j = t; j < HID; j += 256) {
        float hv = hidden[j];
        p0 += hv * P[OFF_WFC2 + j * 2 + 0];
        p1 += hv * P[OFF_WFC2 + j * 2 + 1];
    }
#pragma unroll
    for (int off = 32; off > 0; off >>= 1) {
        p0 += __shfl_down(p0, off);
        p1 += __shfl_down(p1, off);
    }
    int w = t >> 6;
    if ((t & 63) == 0) { r0[w] = p0; r1[w] = p1; }
    __syncthreads();
    if (t == 0) {
        float l0 = r0[0] + r0[1] + r0[2] + r0[3] + P[OFF_BFC2 + 0];
        float l1 = r1[0] + r1[1] + r1[2] + r1[3] + P[OFF_BFC2 + 1];
        float mx = fmaxf(l0, l1);
        float lse = mx + logf(expf(l0 - mx) + expf(l1 - mx));
        float o0 = l0 - lse, o1 = l1 - lse;
        if (flags[0]) {
            ((__hip_bfloat16*)outv)[g * 2 + 0] = __float2bfloat16(o0);
            ((__hip_bfloat16*)outv)[g * 2 + 1] = __float2bfloat16(o1);
        } else {
            ((float*)outv)[g * 2 + 0] = o0;
            ((float*)outv)[g * 2 + 1] = o1;
        }
    }
}

extern "C" void kernel_launch(void* const* d_in, const int* in_sizes, int n_in,
                              void* d_out, int out_size, void* d_ws, size_t ws_size,
                              hipStream_t stream)
{
    const void* x     = d_in[0];
    const void* ei    = d_in[17];
    const void* batch = d_in[18];

    float* ws   = (float*)d_ws;
    float* P    = ws;
    float* xr   = P + P_TOTAL;                 // N*96 fp32 (shared by both layers)
    float* h2p  = xr + (size_t)NN * DD;        // G*96 fp32

    __half* hp   = (__half*)(h2p + (size_t)GG * DD);
    __half* xh   = hp;                                // N*128 fp16
    __half* xlh  = xh + (size_t)NN * INDIM;           // N*96 fp16 (layer-1 xl)
    __half* xl2h = xlh + (size_t)NN * DD;             // N*96 fp16 (layer-2 xl)
    __half* h1h  = xl2h + (size_t)NN * DD;            // N*96 fp16
    __half* B1   = h1h + (size_t)NN * DD;             // 24576
    __half* B2   = B1 + 24576;                        // 18432

    int* ip      = (int*)(B2 + 18432);
    int* deg     = ip;                 // NN, zeroed by memset
    int* pooled  = deg + NN;           // NN, zeroed
    int* needed  = pooled + NN;        // NN, zeroed
    int* cnt     = needed + NN;        // 4 incl pad, zeroed
    int* csr     = cnt + 4;            // NN*CAP (fixed stride)
    int* list    = csr + (size_t)NN * CAP; // NN
    int* first   = list + NN;          // GG
    int* flags   = first + GG;         // 4

    ParamTab t;
    const int sz[16]  = {12288, 96, 12288, 96, 96, 96, 9216, 96, 9216, 96, 96, 96, 98304, 512, 1024, 2};
    const int off[16] = {OFF_WL1, OFF_BL1, OFF_WR1, OFF_BR1, OFF_ATT1, OFF_BIAS1,
                         OFF_WL2, OFF_BL2, OFF_WR2, OFF_BR2, OFF_ATT2, OFF_BIAS2,
                         OFF_WFC1, OFF_BFC1, OFF_WFC2, OFF_BFC2};
    for (int i = 0; i < 16; i++) { t.p[i] = d_in[1 + i]; t.sz[i] = sz[i]; t.off[i] = off[i]; }

    const int edge4B = (EE / 4 + 255) / 256;  // 1563
    const int nodeB = (NN + 255) / 256;       // 196
    const int mprojB = (NN + 63) / 64;        // 782
    const int fuse1B = 2048;                  // persistent: 8192 waves
    const int fuse2B = (GG * 3) / 4;          // 384

    detect_kernel<<<1, 256, 0, stream>>>(x, ei, flags);
    convert_params_kernel<<<dim3(96, 16), 256, 0, stream>>>(t, flags, P);
    build_bswz_kernel<<<12, 256, 0, stream>>>(P, OFF_WL1, OFF_WR1, 4, B1);
    build_bswz_kernel<<<9, 256, 0, stream>>>(P, OFF_WL2, OFF_WR2, 3, B2);
    conv_x_kernel<<<(NN * INDIM / 4 + 255) / 256, 256, 0, stream>>>(x, flags, xh);
    (void)hipMemsetAsync(deg, 0, (size_t)(3 * NN + 4) * sizeof(int), stream);

    firstpool_kernel<<<nodeB, 256, 0, stream>>>(batch, flags, first, pooled, needed);
    mark_needed_kernel<<<edge4B, 256, 0, stream>>>(ei, flags, pooled, needed);
    compact_kernel<<<nodeB, 256, 0, stream>>>(needed, list, cnt);

    scatter_fixed_kernel<<<edge4B, 256, 0, stream>>>(ei, flags, needed, deg, csr);

    // ---- layer 1 ----
    proj_mfma_kernel<INDIM, 0><<<mprojB, 256, 0, stream>>>(xh, B1, nullptr, nullptr,
                                                           P, OFF_BL1, OFF_BR1, xlh, xr);
    fused_edge_kernel<0><<<fuse1B, 256, 0, stream>>>(csr, deg, list, cnt, xlh, xr,
                                                     P, OFF_ATT1, OFF_BIAS1, (void*)h1h);

    // ---- layer 2 ----
    proj_mfma_kernel<DD, 1><<<mprojB, 256, 0, stream>>>(h1h, B2, list, cnt,
                                                        P, OFF_BL2, OFF_BR2, xl2h, xr);
    fused_edge_kernel<1><<<fuse2B, 256, 0, stream>>>(csr, deg, first, nullptr, xl2h, xr,
                                                     P, OFF_ATT2, OFF_BIAS2, (void*)h2p);

    // ---- head ----
    mlp_kernel<<<GG, 256, 0, stream>>>(h1h, h2p, P, flags, first, d_out);
}

// Round 9
// 280.943 us; speedup vs baseline: 1.0765x; 1.0765x over previous
//
#include <hip/hip_runtime.h>
#include <hip/hip_bf16.h>
#include <hip/hip_fp16.h>
#include <math.h>

#define NN 50000
#define EE 1600000
#define GG 512
#define INDIM 128
#define HEADS 3
#define CC 32
#define DD 96            // HEADS*CC
#define HID 512
#define NEG 0.2f
#define EPS_DEN 1e-16f
#define CAP 128          // fixed CSR row capacity (mean degree 32, sigma 5.7 -> 17 sigma headroom)
#define MNEG -1e30f      // empty-partial sentinel (finite: avoids -inf-(-inf)=NaN in merges)

// packed fp32 param block offsets (in floats)
#define OFF_WL1   0
#define OFF_BL1   12288
#define OFF_WR1   12384
#define OFF_BR1   24672
#define OFF_ATT1  24768
#define OFF_BIAS1 24864
#define OFF_WL2   24960
#define OFF_BL2   34176
#define OFF_WR2   34272
#define OFF_BR2   43488
#define OFF_ATT2  43584
#define OFF_BIAS2 43680
#define OFF_WFC1  43776
#define OFF_BFC1  142080
#define OFF_WFC2  142592
#define OFF_BFC2  143616
#define P_TOTAL   143744

typedef _Float16 h8 __attribute__((ext_vector_type(8)));
typedef float f4 __attribute__((ext_vector_type(4)));

static __device__ __forceinline__ float bf2f(__hip_bfloat16 v) { return __bfloat162float(v); }

// index fetch tolerant of int64-vs-int32 storage (little-endian, values < 2^31)
static __device__ __forceinline__ int getI(const void* p, long long i, bool w64) {
    return w64 ? ((const int*)p)[2 * i] : ((const int*)p)[i];
}

// load 4 consecutive edge indices starting at element (base+e0); e0 multiple of 4, base even
static __device__ __forceinline__ void load4(const void* p, int base, int e0, bool w64, int* v) {
    const int4* q = (const int4*)p;
    if (w64) {
        int4 a = q[(base + e0) >> 1];
        int4 b = q[((base + e0) >> 1) + 1];
        v[0] = a.x; v[1] = a.z; v[2] = b.x; v[3] = b.z;
    } else {
        int4 a = q[(base + e0) >> 2];
        v[0] = a.x; v[1] = a.y; v[2] = a.z; v[3] = a.w;
    }
}

// ---------------- dtype detection ----------------
__global__ void detect_kernel(const void* __restrict__ x, const void* __restrict__ ei,
                              int* __restrict__ flags)
{
    __shared__ int wild, zcnt;
    if (threadIdx.x == 0) { wild = 0; zcnt = 0; }
    __syncthreads();
    int w = 0, z = 0;
    const __hip_bfloat16* xb = (const __hip_bfloat16*)x;
    for (int i = threadIdx.x; i < 4096; i += 256) {
        float v = bf2f(xb[i]);
        if (!(fabsf(v) <= 1e6f)) w++;
    }
    const int* e32 = (const int*)ei;
    for (int i = threadIdx.x; i < 4096; i += 256) {
        if (e32[2 * i + 1] == 0) z++;
    }
    atomicAdd(&wild, w);
    atomicAdd(&zcnt, z);
    __syncthreads();
    if (threadIdx.x == 0) {
        flags[0] = (wild < 64) ? 1 : 0;   // 1 => floats are bf16
        flags[1] = (zcnt > 4000) ? 1 : 0; // 1 => ints are int64
    }
}

// ---------------- convert all weight tensors to packed fp32 ----------------
struct ParamTab { const void* p[16]; int sz[16]; int off[16]; };

__global__ void convert_params_kernel(ParamTab t, const int* __restrict__ flags,
                                      float* __restrict__ P)
{
    const int which = blockIdx.y;
    const int n = t.sz[which];
    const void* src = t.p[which];
    float* dst = P + t.off[which];
    const bool isbf = flags[0] != 0;
    for (int i = blockIdx.x * 256 + threadIdx.x; i < n; i += gridDim.x * 256) {
        dst[i] = isbf ? bf2f(((const __hip_bfloat16*)src)[i]) : ((const float*)src)[i];
    }
}

// ---------------- build MFMA-swizzled fp16 B matrix (Wl | Wr), [ntile][kc][lane][8] ----------------
__global__ void build_bswz_kernel(const float* __restrict__ P, int offWl, int offWr, int KC,
                                  __half* __restrict__ B)
{
    int idx = blockIdx.x * 256 + threadIdx.x;
    int total = 12 * KC * 64;
    if (idx >= total) return;
    int lane = idx & 63;
    int t = idx >> 6;
    int kc = t % KC;
    int ntile = t / KC;
    int n = ntile * 16 + (lane & 15);
    int kbase = kc * 32 + (lane >> 4) * 8;
    const float* Wsrc = (n < 96) ? (P + offWl) : (P + offWr);
    int n2 = (n < 96) ? n : n - 96;
    __half* dst = B + (size_t)idx * 8;
#pragma unroll
    for (int j = 0; j < 8; j++) dst[j] = __float2half(Wsrc[(kbase + j) * 96 + n2]);
}

// ---------------- pooling set ----------------
__global__ void firstpool_kernel(const void* __restrict__ batch, const int* __restrict__ flags,
                                 int* __restrict__ first, int* __restrict__ pooled,
                                 int* __restrict__ needed)
{
    int i = blockIdx.x * 256 + threadIdx.x;
    if (i >= NN) return;
    const bool w64 = flags[1] != 0;
    int b = getI(batch, i, w64);
    if (i == 0 || getI(batch, i - 1, w64) != b) {
        first[b] = i;
        pooled[i] = 1;
        needed[i] = 1;
    }
}

// needed[src]=1 for every edge landing on a pooled dst (4 edges/thread)
__global__ void mark_needed_kernel(const void* __restrict__ ei, const int* __restrict__ flags,
                                   const int* __restrict__ pooled, int* __restrict__ needed)
{
    int e0 = (blockIdx.x * 256 + threadIdx.x) * 4;
    if (e0 >= EE) return;
    const bool w64 = flags[1] != 0;
    int s4[4], d4[4];
    load4(ei, EE, e0, w64, d4);
    load4(ei, 0, e0, w64, s4);
#pragma unroll
    for (int j = 0; j < 4; j++) if (pooled[d4[j]]) needed[s4[j]] = 1;
}

__global__ void compact_kernel(const int* __restrict__ needed, int* __restrict__ list,
                               int* __restrict__ cnt)
{
    int i = blockIdx.x * 256 + threadIdx.x;
    if (i >= NN) return;
    if (needed[i]) list[atomicAdd(cnt, 1)] = i;
}

// ---------------- filtered fixed-stride CSR scatter (4 edges/thread) ----------------
__global__ void scatter_fixed_kernel(const void* __restrict__ ei, const int* __restrict__ flags,
                                     const int* __restrict__ needed,
                                     int* __restrict__ deg, int* __restrict__ csr)
{
    int e0 = (blockIdx.x * 256 + threadIdx.x) * 4;
    if (e0 >= EE) return;
    const bool w64 = flags[1] != 0;
    int s4[4], d4[4];
    load4(ei, EE, e0, w64, d4);
    load4(ei, 0, e0, w64, s4);
#pragma unroll
    for (int j = 0; j < 4; j++) {
        int dst = d4[j];
        if (!needed[dst]) continue;
        int pos = atomicAdd(&deg[dst], 1);
        if (pos < CAP) csr[(size_t)dst * CAP + pos] = s4[j];
    }
}

// ---------------- MFMA projection: rows @ (Wl|Wr)[K,192] + b -> xl (fp16), xr (fp32) ----------------
// MODE 0: dense rows from raw x (dtype per flags[0]); MODE 1: rows from list, input fp16 h1h
template <int KDIM, int MODE>
__global__ __launch_bounds__(256) void proj_mfma_kernel(
    const void* __restrict__ Ain, const __half* __restrict__ Bswz,
    const int* __restrict__ list, const int* __restrict__ cnt,
    const float* __restrict__ P, const int* __restrict__ flags, int offBl, int offBr,
    __half* __restrict__ xl, float* __restrict__ xr)
{
    constexpr int KC = KDIM / 32;
    __shared__ __half Bs[12 * KC * 64 * 8];
    const int tid = threadIdx.x;
    const int limit = MODE ? *cnt : NN;
    const int blockBase = blockIdx.x * 64;
    if (blockBase >= limit) return;

    {
        const int chunks = 12 * KC * 64;
        for (int i = tid; i < chunks; i += 256)
            reinterpret_cast<f4*>(Bs)[i] = reinterpret_cast<const f4*>(Bswz)[i];
    }
    __syncthreads();

    const int wave = tid >> 6;
    const int lane = tid & 63;
    const int base = blockBase + wave * 16;
    if (base >= limit) return;

    const int q = lane >> 4;
    const int mlane = lane & 15;

    int aIdx = base + mlane;
    int aRow;
    if (MODE) aRow = (aIdx < limit) ? list[aIdx] : list[limit - 1];
    else      aRow = (aIdx < limit) ? aIdx : 0;

    h8 a[KC];
    if (MODE == 1) {
        const h8* arow = reinterpret_cast<const h8*>((const __half*)Ain + (size_t)aRow * KDIM);
#pragma unroll
        for (int kc = 0; kc < KC; kc++) a[kc] = arow[kc * 4 + q];
    } else if (flags[0]) {
        // bf16 input: 16B load, shift-unpack to fp16 (exact: bf16 mantissa < fp16 mantissa)
        const int4* arow = reinterpret_cast<const int4*>((const ushort*)Ain + (size_t)aRow * KDIM);
#pragma unroll
        for (int kc = 0; kc < KC; kc++) {
            int4 r = arow[kc * 4 + q];
            int ws[4] = {r.x, r.y, r.z, r.w};
#pragma unroll
            for (int i = 0; i < 4; i++) {
                a[kc][2 * i]     = (_Float16)__int_as_float(ws[i] << 16);
                a[kc][2 * i + 1] = (_Float16)__int_as_float(ws[i] & 0xffff0000);
            }
        }
    } else {
        // fp32 input: 2x16B loads, convert
        const f4* arow = reinterpret_cast<const f4*>((const float*)Ain + (size_t)aRow * KDIM);
#pragma unroll
        for (int kc = 0; kc < KC; kc++) {
            f4 r0 = arow[kc * 8 + q * 2];
            f4 r1 = arow[kc * 8 + q * 2 + 1];
#pragma unroll
            for (int i = 0; i < 4; i++) {
                a[kc][i]     = (_Float16)r0[i];
                a[kc][4 + i] = (_Float16)r1[i];
            }
        }
    }

    int sRow[4];
#pragma unroll
    for (int r = 0; r < 4; r++) {
        int si = base + q * 4 + r;
        sRow[r] = (si < limit) ? (MODE ? list[si] : si) : -1;
    }

    const h8* Bf = reinterpret_cast<const h8*>(Bs);
#pragma unroll
    for (int ntile = 0; ntile < 12; ntile++) {
        int n = ntile * 16 + mlane;
        float bv = (n < 96) ? P[offBl + n] : P[offBr + n - 96];
        f4 acc = {bv, bv, bv, bv};
#pragma unroll
        for (int kc = 0; kc < KC; kc++) {
            h8 b = Bf[(ntile * KC + kc) * 64 + lane];
            acc = __builtin_amdgcn_mfma_f32_16x16x32_f16(a[kc], b, acc, 0, 0, 0);
        }
#pragma unroll
        for (int r = 0; r < 4; r++) {
            if (sRow[r] < 0) continue;
            if (n < 96) xl[(size_t)sRow[r] * DD + n] = __float2half(acc[r]);
            else        xr[(size_t)sRow[r] * DD + (n - 96)] = acc[r];
        }
    }
}

// ---------------- fused edge: per-(dst,head) wave (half-wave per edge), online softmax ----------------
// r7 structure, unroll x4 per half-wave -> 8 gathers in flight per wave.
// OUTMODE 0: dst from list[0..*cnt), output fp16 h1h; OUTMODE 1: dst=first[g], output fp32 h2p
template <int OUTMODE>
__global__ __launch_bounds__(256) void fused_edge_kernel(
    const int* __restrict__ csr, const int* __restrict__ deg,
    const int* __restrict__ list, const int* __restrict__ cnt,
    const __half* __restrict__ xl, const float* __restrict__ xr,
    const float* __restrict__ P, int offAtt, int offBias,
    void* __restrict__ out)
{
    const int lane = threadIdx.x & 63;
    const int c = lane & 31;
    const int eo = lane >> 5;
    const int w0 = (blockIdx.x * 256 + threadIdx.x) >> 6;
    const int nw = (gridDim.x * 256) >> 6;
    const int limit = (OUTMODE == 0) ? *cnt : GG;
    const int items = limit * 3;

    for (int item = w0; item < items; item += nw) {
        const int li = item / 3;
        const int h = item - li * 3;
        const int n = list[li];
        const int hc = h * CC + c;

        const float attc = P[offAtt + hc];
        const float xr_c = xr[(size_t)n * DD + hc];

        float m, d, o;
        {
            // self-loop handled by half-wave 0
            float xls = __half2float(xl[(size_t)n * DD + hc]);
            float s = xls + xr_c;
            s = s > 0.0f ? s : NEG * s;
            float p = s * attc;
#pragma unroll
            for (int off = 16; off; off >>= 1) p += __shfl_xor(p, off, 32);
            if (eo == 0) { m = p; d = 1.0f; o = xls; }
            else         { m = MNEG; d = 0.0f; o = 0.0f; }
        }

        const int* row = csr + (size_t)n * CAP;
        const int end = min(deg[n], CAP);
        int k = eo;
        // unroll x4 per half-wave: 8 gathers in flight per wave
        for (; k + 6 < end; k += 8) {
            int s0 = row[k], s1 = row[k + 2], s2 = row[k + 4], s3 = row[k + 6];
            float x0 = __half2float(xl[(size_t)s0 * DD + hc]);
            float x1 = __half2float(xl[(size_t)s1 * DD + hc]);
            float x2 = __half2float(xl[(size_t)s2 * DD + hc]);
            float x3 = __half2float(xl[(size_t)s3 * DD + hc]);
            float t0 = x0 + xr_c; t0 = t0 > 0.0f ? t0 : NEG * t0;
            float t1 = x1 + xr_c; t1 = t1 > 0.0f ? t1 : NEG * t1;
            float t2 = x2 + xr_c; t2 = t2 > 0.0f ? t2 : NEG * t2;
            float t3 = x3 + xr_c; t3 = t3 > 0.0f ? t3 : NEG * t3;
            float q0 = t0 * attc, q1 = t1 * attc, q2 = t2 * attc, q3 = t3 * attc;
#pragma unroll
            for (int off = 16; off; off >>= 1) {
                q0 += __shfl_xor(q0, off, 32);
                q1 += __shfl_xor(q1, off, 32);
                q2 += __shfl_xor(q2, off, 32);
                q3 += __shfl_xor(q3, off, 32);
            }
            if (q0 <= m) { float e = __expf(q0 - m); d += e; o += e * x0; }
            else         { float r2 = __expf(m - q0); d = d * r2 + 1.0f; o = o * r2 + x0; m = q0; }
            if (q1 <= m) { float e = __expf(q1 - m); d += e; o += e * x1; }
            else         { float r2 = __expf(m - q1); d = d * r2 + 1.0f; o = o * r2 + x1; m = q1; }
            if (q2 <= m) { float e = __expf(q2 - m); d += e; o += e * x2; }
            else         { float r2 = __expf(m - q2); d = d * r2 + 1.0f; o = o * r2 + x2; m = q2; }
            if (q3 <= m) { float e = __expf(q3 - m); d += e; o += e * x3; }
            else         { float r2 = __expf(m - q3); d = d * r2 + 1.0f; o = o * r2 + x3; m = q3; }
        }
        for (; k < end; k += 2) {
            int src = row[k];
            float xv = __half2float(xl[(size_t)src * DD + hc]);
            float s = xv + xr_c;
            s = s > 0.0f ? s : NEG * s;
            float p = s * attc;
#pragma unroll
            for (int off = 16; off; off >>= 1) p += __shfl_xor(p, off, 32);
            if (p <= m) { float e = __expf(p - m); d += e; o += e * xv; }
            else        { float r2 = __expf(m - p); d = d * r2 + 1.0f; o = o * r2 + xv; m = p; }
        }

        // merge the two half-wave states
        float m2 = __shfl_xor(m, 32);
        float d2 = __shfl_xor(d, 32);
        float o2 = __shfl_xor(o, 32);
        float nm = fmaxf(m, m2);
        float e1 = __expf(m - nm), e2 = __expf(m2 - nm);
        d = d * e1 + d2 * e2;
        o = o * e1 + o2 * e2;

        float res = tanhf(o / (d + EPS_DEN) + P[offBias + hc]);
        if (eo == 0) {
            if (OUTMODE == 0) ((__half*)out)[(size_t)n * DD + hc] = __float2half(res);
            else              ((float*)out)[(size_t)li * DD + hc] = res;
        }
    }
}

// ---------------- per-graph MLP head + log_softmax ----------------
__global__ __launch_bounds__(256) void mlp_kernel(
    const __half* __restrict__ h1h, const float* __restrict__ h2p,
    const float* __restrict__ P, const int* __restrict__ flags,
    const int* __restrict__ first, void* __restrict__ outv)
{
    __shared__ float pooled[2 * DD];
    __shared__ float hidden[HID];
    __shared__ float r0[4], r1[4];
    const int g = blockIdx.x;
    const int t = threadIdx.x;
    const int row = first[g];

    if (t < DD) pooled[t] = __half2float(h1h[(size_t)row * DD + t]);
    else if (t < 2 * DD) pooled[t] = h2p[(size_t)g * DD + (t - DD)];
    __syncthreads();

    for (int col = t; col < HID; col += 256) {
        float acc = P[OFF_BFC1 + col];
        for (int i = 0; i < 2 * DD; i++) acc += pooled[i] * P[OFF_WFC1 + i * HID + col];
        hidden[col] = fmaxf(acc, 0.0f);
    }
    __syncthreads();

    float p0 = 0.0f, p1 = 0.0f;
    for (int j = t; j < HID; j += 256) {
        float hv = hidden[j];
        p0 += hv * P[OFF_WFC2 + j * 2 + 0];
        p1 += hv * P[OFF_WFC2 + j * 2 + 1];
    }
#pragma unroll
    for (int off = 32; off > 0; off >>= 1) {
        p0 += __shfl_down(p0, off);
        p1 += __shfl_down(p1, off);
    }
    int w = t >> 6;
    if ((t & 63) == 0) { r0[w] = p0; r1[w] = p1; }
    __syncthreads();
    if (t == 0) {
        float l0 = r0[0] + r0[1] + r0[2] + r0[3] + P[OFF_BFC2 + 0];
        float l1 = r1[0] + r1[1] + r1[2] + r1[3] + P[OFF_BFC2 + 1];
        float mx = fmaxf(l0, l1);
        float lse = mx + logf(expf(l0 - mx) + expf(l1 - mx));
        float o0 = l0 - lse, o1 = l1 - lse;
        if (flags[0]) {
            ((__hip_bfloat16*)outv)[g * 2 + 0] = __float2bfloat16(o0);
            ((__hip_bfloat16*)outv)[g * 2 + 1] = __float2bfloat16(o1);
        } else {
            ((float*)outv)[g * 2 + 0] = o0;
            ((float*)outv)[g * 2 + 1] = o1;
        }
    }
}

extern "C" void kernel_launch(void* const* d_in, const int* in_sizes, int n_in,
                              void* d_out, int out_size, void* d_ws, size_t ws_size,
                              hipStream_t stream)
{
    const void* x     = d_in[0];
    const void* ei    = d_in[17];
    const void* batch = d_in[18];

    float* ws   = (float*)d_ws;
    float* P    = ws;
    float* xr   = P + P_TOTAL;                 // N*96 fp32 (shared by both layers)
    float* h2p  = xr + (size_t)NN * DD;        // G*96 fp32

    __half* hp   = (__half*)(h2p + (size_t)GG * DD);
    __half* xlh  = hp;                                // N*96 fp16 (layer-1 xl)
    __half* xl2h = xlh + (size_t)NN * DD;             // N*96 fp16 (layer-2 xl)
    __half* h1h  = xl2h + (size_t)NN * DD;            // N*96 fp16
    __half* B1   = h1h + (size_t)NN * DD;             // 24576
    __half* B2   = B1 + 24576;                        // 18432

    int* ip      = (int*)(B2 + 18432);
    int* deg     = ip;                 // NN, zeroed by memset
    int* pooled  = deg + NN;           // NN, zeroed
    int* needed  = pooled + NN;        // NN, zeroed
    int* cnt     = needed + NN;        // 4 incl pad, zeroed
    int* csr     = cnt + 4;            // NN*CAP (fixed stride)
    int* list    = csr + (size_t)NN * CAP; // NN
    int* first   = list + NN;          // GG
    int* flags   = first + GG;         // 4

    ParamTab t;
    const int sz[16]  = {12288, 96, 12288, 96, 96, 96, 9216, 96, 9216, 96, 96, 96, 98304, 512, 1024, 2};
    const int off[16] = {OFF_WL1, OFF_BL1, OFF_WR1, OFF_BR1, OFF_ATT1, OFF_BIAS1,
                         OFF_WL2, OFF_BL2, OFF_WR2, OFF_BR2, OFF_ATT2, OFF_BIAS2,
                         OFF_WFC1, OFF_BFC1, OFF_WFC2, OFF_BFC2};
    for (int i = 0; i < 16; i++) { t.p[i] = d_in[1 + i]; t.sz[i] = sz[i]; t.off[i] = off[i]; }

    const int edge4B = (EE / 4 + 255) / 256;  // 1563
    const int nodeB = (NN + 255) / 256;       // 196
    const int mprojB = (NN + 63) / 64;        // 782
    const int fuse1B = 2048;                  // persistent: 8192 waves
    const int fuse2B = (GG * 3) / 4;          // 384

    detect_kernel<<<1, 256, 0, stream>>>(x, ei, flags);
    convert_params_kernel<<<dim3(96, 16), 256, 0, stream>>>(t, flags, P);
    build_bswz_kernel<<<12, 256, 0, stream>>>(P, OFF_WL1, OFF_WR1, 4, B1);
    build_bswz_kernel<<<9, 256, 0, stream>>>(P, OFF_WL2, OFF_WR2, 3, B2);
    (void)hipMemsetAsync(deg, 0, (size_t)(3 * NN + 4) * sizeof(int), stream);

    firstpool_kernel<<<nodeB, 256, 0, stream>>>(batch, flags, first, pooled, needed);
    mark_needed_kernel<<<edge4B, 256, 0, stream>>>(ei, flags, pooled, needed);
    compact_kernel<<<nodeB, 256, 0, stream>>>(needed, list, cnt);

    scatter_fixed_kernel<<<edge4B, 256, 0, stream>>>(ei, flags, needed, deg, csr);

    // ---- layer 1: MFMA proj reads raw x directly (conv_x eliminated) ----
    proj_mfma_kernel<INDIM, 0><<<mprojB, 256, 0, stream>>>(x, B1, nullptr, nullptr,
                                                           P, flags, OFF_BL1, OFF_BR1, xlh, xr);
    fused_edge_kernel<0><<<fuse1B, 256, 0, stream>>>(csr, deg, list, cnt, xlh, xr,
                                                     P, OFF_ATT1, OFF_BIAS1, (void*)h1h);

    // ---- layer 2 ----
    proj_mfma_kernel<DD, 1><<<mprojB, 256, 0, stream>>>(h1h, B2, list, cnt,
                                                        P, flags, OFF_BL2, OFF_BR2, xl2h, xr);
    fused_edge_kernel<1><<<fuse2B, 256, 0, stream>>>(csr, deg, first, nullptr, xl2h, xr,
                                                     P, OFF_ATT2, OFF_BIAS2, (void*)h2p);

    // ---- head ----
    mlp_kernel<<<GG, 256, 0, stream>>>(h1h, h2p, P, flags, first, d_out);
}